// Round 7
// baseline (418.737 us; speedup 1.0000x reference)
//
#include <hip/hip_runtime.h>

typedef short bf16x8 __attribute__((ext_vector_type(8)));      // 8 bf16 in 4 VGPRs
typedef float f32x4 __attribute__((ext_vector_type(4)));
typedef unsigned short ushort4v __attribute__((ext_vector_type(4)));
typedef unsigned short ushort8 __attribute__((ext_vector_type(8)));

#define DEVI static __device__ __forceinline__

DEVI unsigned short f2bf(float f) {               // RTNE fp32 -> bf16
    unsigned u = __float_as_uint(f);
    u += 0x7FFFu + ((u >> 16) & 1u);
    return (unsigned short)(u >> 16);
}

DEVI unsigned cvtpk(float lo, float hi) {         // packed fp32x2 -> bf16x2 (RNE)
    unsigned r;
    asm("v_cvt_pk_bf16_f32 %0, %1, %2" : "=v"(r) : "v"(lo), "v"(hi));
    return r;
}

typedef __attribute__((address_space(3))) unsigned int* lds_ptr_t;
typedef const __attribute__((address_space(1))) unsigned int* gbl_ptr_t;
#define GLDS(gp, lp) __builtin_amdgcn_global_load_lds((gbl_ptr_t)(gp), (lds_ptr_t)(lp), 16, 0, 0)

// ---------------- fp32 -> bf16 converts ----------------
__global__ void cvt_kernel(const float* __restrict__ src, unsigned short* __restrict__ dst, int n) {
    int i = (blockIdx.x * 256 + threadIdx.x) * 4;
    if (i >= n) return;
    float4 v = *(const float4*)(src + i);
    ushort4v o;
    o.x = f2bf(v.x); o.y = f2bf(v.y); o.z = f2bf(v.z); o.w = f2bf(v.w);
    *(ushort4v*)(dst + i) = o;
}

__global__ void cvt2_kernel(const float* __restrict__ s0, unsigned short* __restrict__ d0, int n0,
                            const float* __restrict__ s1, unsigned short* __restrict__ d1, int n1) {
    int idx = blockIdx.x * 256 + threadIdx.x;
    const int c0 = n0 >> 2;
    const float* src; unsigned short* dst; int i;
    if (idx < c0) { src = s0; dst = d0; i = idx * 4; }
    else {
        i = (idx - c0) * 4;
        if (i >= n1) return;
        src = s1; dst = d1;
    }
    float4 v = *(const float4*)(src + i);
    ushort4v o;
    o.x = f2bf(v.x); o.y = f2bf(v.y); o.z = f2bf(v.z); o.w = f2bf(v.w);
    *(ushort4v*)(dst + i) = o;
}

// ---------------- bf16 GEMM: 64x128 tile, 2-phase prefetch, counted vmcnt ----------------
// MODE 0: bf16 out [B,NH,S,HD]; MODE 1: fp32 out [M,N];
// MODE 2: bf16 out [B,NH,HD,S] with k-slot permutation (PV zero-shuffle layout)
template <int MODE>
__global__ __launch_bounds__(256) void gemm_bt(const unsigned short* __restrict__ A,
                                               const unsigned short* __restrict__ W,
                                               const float* __restrict__ bias,
                                               void* __restrict__ Cout) {
    constexpr int K = 1024;
    __shared__ unsigned short Asb[2][64 * 32];
    __shared__ unsigned short Bsb[2][128 * 32];
    const int t = threadIdx.x;
    const int w = t >> 6, l = t & 63;
    const int wr = w >> 1, wc = w & 1;
    const int fr = l & 15, fg = l >> 4;
    const int m0 = blockIdx.y * 64, n0 = blockIdx.x * 128;

    const int ra = t >> 2, qa = (t & 3) * 8;
    const int c1 = 256 + t, rb1 = c1 >> 2, qb1 = (c1 & 3) * 8;

    f32x4 acc[2][4] = {};

#define STG(kb, pb)                                                        \
    {                                                                      \
        GLDS(A + (size_t)(m0 + ra) * K + (kb) + qa, &Asb[pb][t * 8]);      \
        GLDS(W + (size_t)(n0 + ra) * K + (kb) + qa, &Bsb[pb][t * 8]);      \
        GLDS(W + (size_t)(n0 + rb1) * K + (kb) + qb1, &Bsb[pb][c1 * 8]);   \
    }

    STG(0, 0);
    for (int t2 = 0; t2 < 32; ++t2) {
        const int cur = t2 & 1;
        if (t2 < 31) {
            STG((t2 + 1) * 32, cur ^ 1);
            asm volatile("s_waitcnt vmcnt(3)" ::: "memory");
        } else {
            asm volatile("s_waitcnt vmcnt(0)" ::: "memory");
        }
        __syncthreads();
        bf16x8 af[2], bfv[4];
#pragma unroll
        for (int mi = 0; mi < 2; mi++)
            af[mi] = *(const bf16x8*)(&Asb[cur][(wr * 32 + mi * 16 + fr) * 32 + fg * 8]);
#pragma unroll
        for (int ni = 0; ni < 4; ni++)
            bfv[ni] = *(const bf16x8*)(&Bsb[cur][(wc * 64 + ni * 16 + fr) * 32 + fg * 8]);
#pragma unroll
        for (int mi = 0; mi < 2; mi++)
#pragma unroll
            for (int ni = 0; ni < 4; ni++)
                acc[mi][ni] = __builtin_amdgcn_mfma_f32_16x16x32_bf16(af[mi], bfv[ni], acc[mi][ni], 0, 0, 0);
        __syncthreads();
    }
#undef STG

#pragma unroll
    for (int ni = 0; ni < 4; ni++) {
        const int n = n0 + wc * 64 + ni * 16 + fr;
        const float bv = bias[n];
#pragma unroll
        for (int mi = 0; mi < 2; mi++) {
            const int mb = m0 + wr * 32 + mi * 16 + fg * 4;
            if constexpr (MODE == 1) {
                float* C = (float*)Cout;
#pragma unroll
                for (int r = 0; r < 4; r++) C[(size_t)(mb + r) * 1024 + n] = acc[mi][ni][r] + bv;
            } else if constexpr (MODE == 0) {
                unsigned short* C = (unsigned short*)Cout;
                const int h = n >> 6, hd = n & 63;
#pragma unroll
                for (int r = 0; r < 4; r++) {
                    const int m = mb + r;
                    const int bb = m >> 11, s = m & 2047;
                    C[(size_t)((bb * 16 + h) * 2048 + s) * 64 + hd] = f2bf(acc[mi][ni][r] + bv);
                }
            } else {  // MODE 2: vt[B,NH,HD,S] with per-64 k-slot permutation
                unsigned short* C = (unsigned short*)Cout;
                const int h = n >> 6, hd = n & 63;
                const int bb = mb >> 11, s = mb & 2047;
                const int blk = s >> 6, off = s & 63;
                const int pos = blk * 64 + (off >> 5) * 32 + ((off & 15) >> 2) * 8 + ((off >> 4) & 1) * 4;
                ushort4v pk;
                pk.x = f2bf(acc[mi][ni][0] + bv);
                pk.y = f2bf(acc[mi][ni][1] + bv);
                pk.z = f2bf(acc[mi][ni][2] + bv);
                pk.w = f2bf(acc[mi][ni][3] + bv);
                *(ushort4v*)(C + (size_t)((bb * 16 + h) * 64 + hd) * 2048 + pos) = pk;
            }
        }
    }
}

// ---------------- fused attention v6: one-pass, phase-separated stores ----------------
// Same data layout & math as v5, but strict phase order per wave:
//   [QK^T+exp+pack] -> [rinv] -> [PV (loads only)] -> [all attn nt-stores] -> [O reduce]
// so no load ever queues behind a store in the same wave's vmcnt FIFO.
__global__ __launch_bounds__(256, 3) void attn_kernel(const unsigned short* __restrict__ Qh,
                                                      const unsigned short* __restrict__ Kh,
                                                      const unsigned short* __restrict__ Vt,
                                                      unsigned short* __restrict__ Obuf,
                                                      float* __restrict__ AttnOut) {
    __shared__ float rpart[16][4];
    __shared__ float rinv_s[16];
    __shared__ float ored[16][68];

    const int i = blockIdx.x;
    const int bh = (i & 7) * 4 + (i >> 10);      // XCD-grouped head
    const int q0 = ((i >> 3) & 127) * 16;
    const int b = bh >> 4, h = bh & 15;
    const int t = threadIdx.x, w = t >> 6, l = t & 63;
    const int fr = l & 15, fg = l >> 4;
    const float SCL = 0.1803368801111f;          // 0.125 / ln(2)

    const unsigned short* qb = Qh + (size_t)(bh * 2048 + q0) * 64;
    const bf16x8 qf0 = *(const bf16x8*)(qb + (size_t)fr * 64 + fg * 8);
    const bf16x8 qf1 = *(const bf16x8*)(qb + (size_t)fr * 64 + 32 + fg * 8);

    const unsigned short* kbase = Kh + ((size_t)bh * 2048 + w * 512) * 64;
    const unsigned short* vtb = Vt + (size_t)bh * 64 * 2048;

    // ---- phase 1: QK^T sweep, exp (unnormalized) packed bf16 in registers + row-sum ----
    unsigned p[8][8];
    float rs = 0.f;
#pragma unroll
    for (int kt = 0; kt < 8; ++kt) {
#pragma unroll
        for (int mt = 0; mt < 4; ++mt) {
            const unsigned short* kr = kbase + (size_t)(kt * 64 + mt * 16 + fr) * 64 + fg * 8;
            bf16x8 kf0 = *(const bf16x8*)kr;
            bf16x8 kf1 = *(const bf16x8*)(kr + 32);
            f32x4 d = {};
            d = __builtin_amdgcn_mfma_f32_16x16x32_bf16(kf0, qf0, d, 0, 0, 0);
            d = __builtin_amdgcn_mfma_f32_16x16x32_bf16(kf1, qf1, d, 0, 0, 0);
            const float e0 = exp2f(d[0] * SCL), e1 = exp2f(d[1] * SCL);
            const float e2 = exp2f(d[2] * SCL), e3 = exp2f(d[3] * SCL);
            rs += (e0 + e1) + (e2 + e3);
            p[kt][mt * 2] = cvtpk(e0, e1);
            p[kt][mt * 2 + 1] = cvtpk(e2, e3);
        }
    }
    // ---- phase 2: rinv ----
    rs += __shfl_xor(rs, 16, 64);
    rs += __shfl_xor(rs, 32, 64);
    if (l < 16) rpart[l][w] = rs;
    __syncthreads();
    for (int j = t; j < 16 * 68; j += 256) (&ored[0][0])[j] = 0.f;
    if (t < 16) rinv_s[t] = 1.0f / (rpart[t][0] + rpart[t][1] + rpart[t][2] + rpart[t][3]);
    __syncthreads();
    const float ri = rinv_s[fr];

    // ---- phase 3: PV (loads only — no stores ahead of these in the wave's FIFO) ----
    f32x4 opv[4] = {};
#pragma unroll
    for (int kt = 0; kt < 8; ++kt) {
#pragma unroll
        for (int kc = 0; kc < 2; ++kc) {
            union { unsigned u[4]; bf16x8 v; } pb;
            pb.u[0] = p[kt][4 * kc + 0];
            pb.u[1] = p[kt][4 * kc + 1];
            pb.u[2] = p[kt][4 * kc + 2];
            pb.u[3] = p[kt][4 * kc + 3];
#pragma unroll
            for (int dt = 0; dt < 4; ++dt) {
                bf16x8 vf = *(const bf16x8*)(vtb + (size_t)(dt * 16 + fr) * 2048 + w * 512 + kt * 64 + kc * 32 + fg * 8);
                opv[dt] = __builtin_amdgcn_mfma_f32_16x16x32_bf16(vf, pb.v, opv[dt], 0, 0, 0);
            }
        }
    }

    // ---- phase 4: all attn stores, back-to-back fire-and-forget stream ----
    {
        float* attnB = AttnOut + (size_t)bh * 2048 * 2048 + (size_t)(q0 + fr) * 2048 + w * 512;
#pragma unroll
        for (int kt = 0; kt < 8; ++kt) {
#pragma unroll
            for (int mt = 0; mt < 4; ++mt) {
                const unsigned a = p[kt][mt * 2], c = p[kt][mt * 2 + 1];
                f32x4 o;
                o[0] = __uint_as_float(a << 16) * ri;
                o[1] = __uint_as_float(a & 0xffff0000u) * ri;
                o[2] = __uint_as_float(c << 16) * ri;
                o[3] = __uint_as_float(c & 0xffff0000u) * ri;
                __builtin_nontemporal_store(o, (f32x4*)(attnB + kt * 64 + mt * 16 + fg * 4));
            }
        }
    }

    // ---- phase 5: cross-wave O reduction (LDS only; overlaps store drain) ----
    __syncthreads();
    for (int ww = 0; ww < 4; ++ww) {
        if (w == ww) {
#pragma unroll
            for (int dt = 0; dt < 4; dt++)
#pragma unroll
                for (int r = 0; r < 4; r++)
                    ored[fr][dt * 16 + 4 * fg + r] += opv[dt][r];
        }
        __syncthreads();
    }
    {
        const int row = t >> 4, cb = (t & 15) * 4;
        const float rr = rinv_s[row];
        ushort4v pk;
#pragma unroll
        for (int j = 0; j < 4; j++) pk[j] = f2bf(ored[row][cb + j] * rr);
        *(ushort4v*)(Obuf + (size_t)(b * 2048 + q0 + row) * 1024 + h * 64 + cb) = pk;
    }
}

extern "C" void kernel_launch(void* const* d_in, const int* in_sizes, int n_in,
                              void* d_out, int out_size, void* d_ws, size_t ws_size,
                              hipStream_t stream) {
    const float* q = (const float*)d_in[0];
    const float* k = (const float*)d_in[1];
    const float* v = (const float*)d_in[2];
    const float* wqw = (const float*)d_in[3];
    const float* wqb = (const float*)d_in[4];
    const float* wkw = (const float*)d_in[5];
    const float* wkb = (const float*)d_in[6];
    const float* wvw = (const float*)d_in[7];
    const float* wvb = (const float*)d_in[8];
    const float* wow = (const float*)d_in[9];
    const float* wob = (const float*)d_in[10];

    char* ws = (char*)d_ws;
    unsigned short* xbf  = (unsigned short*)(ws);              // 8 MB staging (reused q,k,v)
    unsigned short* wbf  = (unsigned short*)(ws + 8388608);    // 2 MB weight staging (reused)
    unsigned short* qh   = (unsigned short*)(ws + 10485760);   // [B,NH,S,HD] bf16
    unsigned short* kh   = (unsigned short*)(ws + 18874368);   // [B,NH,S,HD] bf16
    unsigned short* vt   = (unsigned short*)(ws + 27262976);   // [B,NH,HD,S] bf16, k-permuted
    unsigned short* obuf = (unsigned short*)(ws + 35651584);   // [B*S,H] bf16

    float* finalOut = (float*)d_out;
    float* attnOut = finalOut + 4194304;

    const int NX = 4194304, NW = 1048576;
    const int c2grid = (NX + NW) / 1024;
    dim3 gGrid(8, 64);

    cvt2_kernel<<<c2grid, 256, 0, stream>>>(q, xbf, NX, wqw, wbf, NW);
    gemm_bt<0><<<gGrid, 256, 0, stream>>>(xbf, wbf, wqb, qh);

    cvt2_kernel<<<c2grid, 256, 0, stream>>>(k, xbf, NX, wkw, wbf, NW);
    gemm_bt<0><<<gGrid, 256, 0, stream>>>(xbf, wbf, wkb, kh);

    cvt2_kernel<<<c2grid, 256, 0, stream>>>(v, xbf, NX, wvw, wbf, NW);
    gemm_bt<2><<<gGrid, 256, 0, stream>>>(xbf, wbf, wvb, vt);

    attn_kernel<<<4096, 256, 0, stream>>>(qh, kh, vt, obuf, attnOut);

    cvt_kernel<<<NW / 1024, 256, 0, stream>>>(wow, wbf, NW);
    gemm_bt<1><<<gGrid, 256, 0, stream>>>(obuf, wbf, wob, finalOut);
}

// Round 8
// 336.313 us; speedup vs baseline: 1.2451x; 1.2451x over previous
//
#include <hip/hip_runtime.h>

typedef short bf16x8 __attribute__((ext_vector_type(8)));      // 8 bf16 in 4 VGPRs
typedef float f32x4 __attribute__((ext_vector_type(4)));
typedef unsigned short ushort4v __attribute__((ext_vector_type(4)));
typedef unsigned short ushort8 __attribute__((ext_vector_type(8)));

#define DEVI static __device__ __forceinline__

DEVI unsigned short f2bf(float f) {               // RTNE fp32 -> bf16
    unsigned u = __float_as_uint(f);
    u += 0x7FFFu + ((u >> 16) & 1u);
    return (unsigned short)(u >> 16);
}

typedef __attribute__((address_space(3))) unsigned int* lds_ptr_t;
typedef const __attribute__((address_space(1))) unsigned int* gbl_ptr_t;
#define GLDS(gp, lp) __builtin_amdgcn_global_load_lds((gbl_ptr_t)(gp), (lds_ptr_t)(lp), 16, 0, 0)

// ---------------- fp32 -> bf16 converts ----------------
__global__ void cvt_kernel(const float* __restrict__ src, unsigned short* __restrict__ dst, int n) {
    int i = (blockIdx.x * 256 + threadIdx.x) * 4;
    if (i >= n) return;
    float4 v = *(const float4*)(src + i);
    ushort4v o;
    o.x = f2bf(v.x); o.y = f2bf(v.y); o.z = f2bf(v.z); o.w = f2bf(v.w);
    *(ushort4v*)(dst + i) = o;
}

__global__ void cvt2_kernel(const float* __restrict__ s0, unsigned short* __restrict__ d0, int n0,
                            const float* __restrict__ s1, unsigned short* __restrict__ d1, int n1) {
    int idx = blockIdx.x * 256 + threadIdx.x;
    const int c0 = n0 >> 2;
    const float* src; unsigned short* dst; int i;
    if (idx < c0) { src = s0; dst = d0; i = idx * 4; }
    else {
        i = (idx - c0) * 4;
        if (i >= n1) return;
        src = s1; dst = d1;
    }
    float4 v = *(const float4*)(src + i);
    ushort4v o;
    o.x = f2bf(v.x); o.y = f2bf(v.y); o.z = f2bf(v.z); o.w = f2bf(v.w);
    *(ushort4v*)(dst + i) = o;
}

// ---------------- bf16 GEMM: 64x128 tile, 2-phase prefetch, counted vmcnt ----------------
template <int MODE>
__global__ __launch_bounds__(256) void gemm_bt(const unsigned short* __restrict__ A,
                                               const unsigned short* __restrict__ W,
                                               const float* __restrict__ bias,
                                               void* __restrict__ Cout) {
    constexpr int K = 1024;
    __shared__ unsigned short Asb[2][64 * 32];
    __shared__ unsigned short Bsb[2][128 * 32];
    const int t = threadIdx.x;
    const int w = t >> 6, l = t & 63;
    const int wr = w >> 1, wc = w & 1;
    const int fr = l & 15, fg = l >> 4;
    const int m0 = blockIdx.y * 64, n0 = blockIdx.x * 128;

    const int ra = t >> 2, qa = (t & 3) * 8;
    const int c1 = 256 + t, rb1 = c1 >> 2, qb1 = (c1 & 3) * 8;

    f32x4 acc[2][4] = {};

#define STG(kb, pb)                                                        \
    {                                                                      \
        GLDS(A + (size_t)(m0 + ra) * K + (kb) + qa, &Asb[pb][t * 8]);      \
        GLDS(W + (size_t)(n0 + ra) * K + (kb) + qa, &Bsb[pb][t * 8]);      \
        GLDS(W + (size_t)(n0 + rb1) * K + (kb) + qb1, &Bsb[pb][c1 * 8]);   \
    }

    STG(0, 0);
    for (int t2 = 0; t2 < 32; ++t2) {
        const int cur = t2 & 1;
        if (t2 < 31) {
            STG((t2 + 1) * 32, cur ^ 1);
            asm volatile("s_waitcnt vmcnt(3)" ::: "memory");
        } else {
            asm volatile("s_waitcnt vmcnt(0)" ::: "memory");
        }
        __syncthreads();
        bf16x8 af[2], bfv[4];
#pragma unroll
        for (int mi = 0; mi < 2; mi++)
            af[mi] = *(const bf16x8*)(&Asb[cur][(wr * 32 + mi * 16 + fr) * 32 + fg * 8]);
#pragma unroll
        for (int ni = 0; ni < 4; ni++)
            bfv[ni] = *(const bf16x8*)(&Bsb[cur][(wc * 64 + ni * 16 + fr) * 32 + fg * 8]);
#pragma unroll
        for (int mi = 0; mi < 2; mi++)
#pragma unroll
            for (int ni = 0; ni < 4; ni++)
                acc[mi][ni] = __builtin_amdgcn_mfma_f32_16x16x32_bf16(af[mi], bfv[ni], acc[mi][ni], 0, 0, 0);
        __syncthreads();
    }
#undef STG

#pragma unroll
    for (int ni = 0; ni < 4; ni++) {
        const int n = n0 + wc * 64 + ni * 16 + fr;
        const float bv = bias[n];
#pragma unroll
        for (int mi = 0; mi < 2; mi++) {
            const int mb = m0 + wr * 32 + mi * 16 + fg * 4;
            if constexpr (MODE == 1) {
                float* C = (float*)Cout;
#pragma unroll
                for (int r = 0; r < 4; r++) C[(size_t)(mb + r) * 1024 + n] = acc[mi][ni][r] + bv;
            } else if constexpr (MODE == 0) {
                unsigned short* C = (unsigned short*)Cout;
                const int h = n >> 6, hd = n & 63;
#pragma unroll
                for (int r = 0; r < 4; r++) {
                    const int m = mb + r;
                    const int bb = m >> 11, s = m & 2047;
                    C[(size_t)((bb * 16 + h) * 2048 + s) * 64 + hd] = f2bf(acc[mi][ni][r] + bv);
                }
            } else {  // MODE 2: vt[B,NH,HD,S]
                unsigned short* C = (unsigned short*)Cout;
                const int h = n >> 6, hd = n & 63;
                const int bb = mb >> 11, s = mb & 2047;
                ushort4v pk;
                pk.x = f2bf(acc[mi][ni][0] + bv);
                pk.y = f2bf(acc[mi][ni][1] + bv);
                pk.z = f2bf(acc[mi][ni][2] + bv);
                pk.w = f2bf(acc[mi][ni][3] + bv);
                *(ushort4v*)(C + (size_t)((bb * 16 + h) * 64 + hd) * 2048 + s) = pk;
            }
        }
    }
}

// ---------------- fused attention v7: R4 two-pass structure + XCD head-grouping ----------------
// 1-D grid 2048: bh = (i&7)*4 + (i>>9) (each XCD owns 4 heads; K+V+Q = 3MB L2-resident),
// qt = (i>>3)&63. Otherwise identical to R4 (best store schedule measured).
__global__ __launch_bounds__(256, 4) void attn_kernel(const unsigned short* __restrict__ Qh,
                                                      const unsigned short* __restrict__ Kh,
                                                      const unsigned short* __restrict__ Vt,
                                                      unsigned short* __restrict__ Obuf,
                                                      float* __restrict__ AttnOut) {
    __shared__ char Plds[32768];  // 2 bufs x 4 waves x 4KB P-tiles [32q][64k] bf16, XOR-swizzled
    __shared__ float rpart[32][4];
    __shared__ float rinv_s[32];

    const int i = blockIdx.x;
    const int bh = (i & 7) * 4 + (i >> 9);
    const int qt = (i >> 3) & 63;
    const int b = bh >> 4, h = bh & 15;
    const int q0 = qt * 32;
    const int t = threadIdx.x, w = t >> 6, l = t & 63;
    const int fr = l & 15, fg = l >> 4;
    const unsigned swz = (unsigned)((fr & 7) << 4);
    const float SCL = 0.1803368801111f;  // 0.125 / ln2

    const unsigned short* qb = Qh + (size_t)(bh * 2048 + q0) * 64;
    bf16x8 qf[2][2];
#pragma unroll
    for (int qs = 0; qs < 2; qs++)
#pragma unroll
        for (int kc = 0; kc < 2; kc++)
            qf[qs][kc] = *(const bf16x8*)(qb + (size_t)(qs * 16 + fr) * 64 + kc * 32 + fg * 8);

    const unsigned short* kbase = Kh + (size_t)bh * 2048 * 64;
    const unsigned short* vtb = Vt + (size_t)bh * 64 * 2048;

    // ---- Pass A: row-sums of exp(s) ----
    float s0 = 0.f, s1 = 0.f;
    for (int kt = 0; kt < 8; ++kt) {
        const int kb = w * 512 + kt * 64;
#pragma unroll
        for (int mt = 0; mt < 4; ++mt) {
            const unsigned short* kr = kbase + (size_t)(kb + mt * 16 + fr) * 64 + fg * 8;
            bf16x8 kf0 = *(const bf16x8*)kr;
            bf16x8 kf1 = *(const bf16x8*)(kr + 32);
            f32x4 d0 = {}, d1 = {};
            d0 = __builtin_amdgcn_mfma_f32_16x16x32_bf16(kf0, qf[0][0], d0, 0, 0, 0);
            d0 = __builtin_amdgcn_mfma_f32_16x16x32_bf16(kf1, qf[0][1], d0, 0, 0, 0);
            d1 = __builtin_amdgcn_mfma_f32_16x16x32_bf16(kf0, qf[1][0], d1, 0, 0, 0);
            d1 = __builtin_amdgcn_mfma_f32_16x16x32_bf16(kf1, qf[1][1], d1, 0, 0, 0);
#pragma unroll
            for (int r = 0; r < 4; r++) {
                s0 += exp2f(d0[r] * SCL);
                s1 += exp2f(d1[r] * SCL);
            }
        }
    }
    s0 += __shfl_xor(s0, 16, 64); s0 += __shfl_xor(s0, 32, 64);
    s1 += __shfl_xor(s1, 16, 64); s1 += __shfl_xor(s1, 32, 64);
    if (l < 16) { rpart[l][w] = s0; rpart[l + 16][w] = s1; }
    __syncthreads();
    if (t < 32) rinv_s[t] = 1.0f / (rpart[t][0] + rpart[t][1] + rpart[t][2] + rpart[t][3]);
    __syncthreads();
    const float ri0 = rinv_s[fr], ri1 = rinv_s[16 + fr];

    // ---- Pass B: pipelined stage/pv (stores interleaved throughout — best measured schedule) ----
    f32x4 opv[2][4] = {};
    float* attnB = AttnOut + (size_t)bh * 2048 * 2048;

#define STAGE(KT)                                                                                   \
    {                                                                                               \
        const int kb = w * 512 + (KT) * 64;                                                         \
        const unsigned pbase = (unsigned)((w + ((KT) & 1) * 4) * 4096);                             \
        _Pragma("unroll") for (int mt = 0; mt < 4; ++mt) {                                          \
            const unsigned short* kr = kbase + (size_t)(kb + mt * 16 + fr) * 64 + fg * 8;           \
            bf16x8 kf0 = *(const bf16x8*)kr;                                                        \
            bf16x8 kf1 = *(const bf16x8*)(kr + 32);                                                 \
            f32x4 d0 = {}, d1 = {};                                                                 \
            d0 = __builtin_amdgcn_mfma_f32_16x16x32_bf16(kf0, qf[0][0], d0, 0, 0, 0);               \
            d0 = __builtin_amdgcn_mfma_f32_16x16x32_bf16(kf1, qf[0][1], d0, 0, 0, 0);               \
            d1 = __builtin_amdgcn_mfma_f32_16x16x32_bf16(kf0, qf[1][0], d1, 0, 0, 0);               \
            d1 = __builtin_amdgcn_mfma_f32_16x16x32_bf16(kf1, qf[1][1], d1, 0, 0, 0);               \
            f32x4 p0, p1;                                                                           \
            _Pragma("unroll") for (int r = 0; r < 4; r++) {                                         \
                p0[r] = exp2f(d0[r] * SCL) * ri0;                                                   \
                p1[r] = exp2f(d1[r] * SCL) * ri1;                                                   \
            }                                                                                       \
            const int kcol = kb + mt * 16 + fg * 4;                                                 \
            __builtin_nontemporal_store(p0, (f32x4*)(attnB + (size_t)(q0 + fr) * 2048 + kcol));     \
            __builtin_nontemporal_store(p1, (f32x4*)(attnB + (size_t)(q0 + 16 + fr) * 2048 + kcol));\
            ushort4v pk0, pk1;                                                                      \
            _Pragma("unroll") for (int r = 0; r < 4; r++) { pk0[r] = f2bf(p0[r]); pk1[r] = f2bf(p1[r]); } \
            const unsigned colb = (unsigned)(mt * 32 + fg * 8) ^ swz;                               \
            *(ushort4v*)(Plds + pbase + (unsigned)fr * 128 + colb) = pk0;                           \
            *(ushort4v*)(Plds + pbase + (unsigned)(16 + fr) * 128 + colb) = pk1;                    \
        }                                                                                           \
    }

#define PVSTEP(KT)                                                                                  \
    {                                                                                               \
        const int kb = w * 512 + (KT) * 64;                                                         \
        const unsigned pbase = (unsigned)((w + ((KT) & 1) * 4) * 4096);                             \
        _Pragma("unroll") for (int kc = 0; kc < 2; ++kc) {                                          \
            const unsigned ro = (unsigned)(kc * 64 + fg * 16) ^ swz;                                \
            bf16x8 pa0 = *(const bf16x8*)(Plds + pbase + (unsigned)fr * 128 + ro);                  \
            bf16x8 pa1 = *(const bf16x8*)(Plds + pbase + (unsigned)(16 + fr) * 128 + ro);           \
            _Pragma("unroll") for (int dt = 0; dt < 4; ++dt) {                                      \
                bf16x8 vf = *(const bf16x8*)(vtb + (size_t)(dt * 16 + fr) * 2048 + kb + kc * 32 + fg * 8); \
                opv[0][dt] = __builtin_amdgcn_mfma_f32_16x16x32_bf16(pa0, vf, opv[0][dt], 0, 0, 0); \
                opv[1][dt] = __builtin_amdgcn_mfma_f32_16x16x32_bf16(pa1, vf, opv[1][dt], 0, 0, 0); \
            }                                                                                       \
        }                                                                                           \
    }

    STAGE(0);
    for (int kt = 1; kt < 8; ++kt) {
        STAGE(kt);
        PVSTEP(kt - 1);
    }
    PVSTEP(7);
#undef STAGE
#undef PVSTEP

    __syncthreads();
    float* ored = (float*)Plds;  // [32][68], aliases P tiles (all PV reads done)
    for (int j = t; j < 32 * 68; j += 256) ored[j] = 0.f;
    __syncthreads();
    for (int ww = 0; ww < 4; ++ww) {
        if (w == ww) {
#pragma unroll
            for (int qs = 0; qs < 2; qs++)
#pragma unroll
                for (int dt = 0; dt < 4; dt++)
#pragma unroll
                    for (int r = 0; r < 4; r++)
                        ored[(qs * 16 + fg * 4 + r) * 68 + dt * 16 + fr] += opv[qs][dt][r];
        }
        __syncthreads();
    }
    {
        const int row = t >> 3, cb = (t & 7) * 8;
        ushort8 pk;
#pragma unroll
        for (int j = 0; j < 8; j++) pk[j] = f2bf(ored[row * 68 + cb + j]);
        *(ushort8*)(Obuf + (size_t)(b * 2048 + q0 + row) * 1024 + h * 64 + cb) = pk;
    }
}

extern "C" void kernel_launch(void* const* d_in, const int* in_sizes, int n_in,
                              void* d_out, int out_size, void* d_ws, size_t ws_size,
                              hipStream_t stream) {
    const float* q = (const float*)d_in[0];
    const float* k = (const float*)d_in[1];
    const float* v = (const float*)d_in[2];
    const float* wqw = (const float*)d_in[3];
    const float* wqb = (const float*)d_in[4];
    const float* wkw = (const float*)d_in[5];
    const float* wkb = (const float*)d_in[6];
    const float* wvw = (const float*)d_in[7];
    const float* wvb = (const float*)d_in[8];
    const float* wow = (const float*)d_in[9];
    const float* wob = (const float*)d_in[10];

    char* ws = (char*)d_ws;
    unsigned short* xbf  = (unsigned short*)(ws);              // 8 MB staging (reused q,k,v)
    unsigned short* wbf  = (unsigned short*)(ws + 8388608);    // 2 MB weight staging (reused)
    unsigned short* qh   = (unsigned short*)(ws + 10485760);   // [B,NH,S,HD] bf16
    unsigned short* kh   = (unsigned short*)(ws + 18874368);   // [B,NH,S,HD] bf16
    unsigned short* vt   = (unsigned short*)(ws + 27262976);   // [B,NH,HD,S] bf16
    unsigned short* obuf = (unsigned short*)(ws + 35651584);   // [B*S,H] bf16

    float* finalOut = (float*)d_out;
    float* attnOut = finalOut + 4194304;

    const int NX = 4194304, NW = 1048576;
    const int c2grid = (NX + NW) / 1024;
    dim3 gGrid(8, 64);

    cvt2_kernel<<<c2grid, 256, 0, stream>>>(q, xbf, NX, wqw, wbf, NW);
    gemm_bt<0><<<gGrid, 256, 0, stream>>>(xbf, wbf, wqb, qh);

    cvt2_kernel<<<c2grid, 256, 0, stream>>>(k, xbf, NX, wkw, wbf, NW);
    gemm_bt<0><<<gGrid, 256, 0, stream>>>(xbf, wbf, wkb, kh);

    cvt2_kernel<<<c2grid, 256, 0, stream>>>(v, xbf, NX, wvw, wbf, NW);
    gemm_bt<2><<<gGrid, 256, 0, stream>>>(xbf, wbf, wvb, vt);

    attn_kernel<<<2048, 256, 0, stream>>>(qh, kh, vt, obuf, attnOut);

    cvt_kernel<<<NW / 1024, 256, 0, stream>>>(wow, wbf, NW);
    gemm_bt<1><<<gGrid, 256, 0, stream>>>(obuf, wbf, wob, finalOut);
}

// Round 9
// 301.851 us; speedup vs baseline: 1.3872x; 1.1142x over previous
//
#include <hip/hip_runtime.h>

typedef short bf16x8 __attribute__((ext_vector_type(8)));      // 8 bf16 in 4 VGPRs
typedef float f32x4 __attribute__((ext_vector_type(4)));
typedef unsigned short ushort4v __attribute__((ext_vector_type(4)));
typedef unsigned short ushort8 __attribute__((ext_vector_type(8)));

#define DEVI static __device__ __forceinline__

DEVI unsigned short f2bf(float f) {               // RTNE fp32 -> bf16
    unsigned u = __float_as_uint(f);
    u += 0x7FFFu + ((u >> 16) & 1u);
    return (unsigned short)(u >> 16);
}

DEVI unsigned cvtpk(float lo, float hi) {         // packed fp32x2 -> bf16x2 (RNE)
    unsigned r;
    asm("v_cvt_pk_bf16_f32 %0, %1, %2" : "=v"(r) : "v"(lo), "v"(hi));
    return r;
}

typedef __attribute__((address_space(3))) unsigned int* lds_ptr_t;
typedef const __attribute__((address_space(1))) unsigned int* gbl_ptr_t;
#define GLDS(gp, lp) __builtin_amdgcn_global_load_lds((gbl_ptr_t)(gp), (lds_ptr_t)(lp), 16, 0, 0)

// ---------------- fp32 -> bf16 converts ----------------
__global__ void cvt_kernel(const float* __restrict__ src, unsigned short* __restrict__ dst, int n) {
    int i = (blockIdx.x * 256 + threadIdx.x) * 4;
    if (i >= n) return;
    float4 v = *(const float4*)(src + i);
    ushort4v o;
    o.x = f2bf(v.x); o.y = f2bf(v.y); o.z = f2bf(v.z); o.w = f2bf(v.w);
    *(ushort4v*)(dst + i) = o;
}

__global__ void cvt2_kernel(const float* __restrict__ s0, unsigned short* __restrict__ d0, int n0,
                            const float* __restrict__ s1, unsigned short* __restrict__ d1, int n1) {
    int idx = blockIdx.x * 256 + threadIdx.x;
    const int c0 = n0 >> 2;
    const float* src; unsigned short* dst; int i;
    if (idx < c0) { src = s0; dst = d0; i = idx * 4; }
    else {
        i = (idx - c0) * 4;
        if (i >= n1) return;
        src = s1; dst = d1;
    }
    float4 v = *(const float4*)(src + i);
    ushort4v o;
    o.x = f2bf(v.x); o.y = f2bf(v.y); o.z = f2bf(v.z); o.w = f2bf(v.w);
    *(ushort4v*)(dst + i) = o;
}

// ---------------- bf16 GEMM: 64x128 tile, 2-phase prefetch, counted vmcnt ----------------
// MODE 0: bf16 out [B,NH,S,HD]; MODE 1: fp32 out [M,N];
// MODE 2: bf16 out [B,NH,HD,S] with per-64 k-slot permutation (PV zero-shuffle layout):
//   off = kc*32 + m16*16 + fg4*4 + r  ->  pos = kc*32 + fg4*8 + m16*4 + r
template <int MODE>
__global__ __launch_bounds__(256) void gemm_bt(const unsigned short* __restrict__ A,
                                               const unsigned short* __restrict__ W,
                                               const float* __restrict__ bias,
                                               void* __restrict__ Cout) {
    constexpr int K = 1024;
    __shared__ unsigned short Asb[2][64 * 32];
    __shared__ unsigned short Bsb[2][128 * 32];
    const int t = threadIdx.x;
    const int w = t >> 6, l = t & 63;
    const int wr = w >> 1, wc = w & 1;
    const int fr = l & 15, fg = l >> 4;
    const int m0 = blockIdx.y * 64, n0 = blockIdx.x * 128;

    const int ra = t >> 2, qa = (t & 3) * 8;
    const int c1 = 256 + t, rb1 = c1 >> 2, qb1 = (c1 & 3) * 8;

    f32x4 acc[2][4] = {};

#define STG(kb, pb)                                                        \
    {                                                                      \
        GLDS(A + (size_t)(m0 + ra) * K + (kb) + qa, &Asb[pb][t * 8]);      \
        GLDS(W + (size_t)(n0 + ra) * K + (kb) + qa, &Bsb[pb][t * 8]);      \
        GLDS(W + (size_t)(n0 + rb1) * K + (kb) + qb1, &Bsb[pb][c1 * 8]);   \
    }

    STG(0, 0);
    for (int t2 = 0; t2 < 32; ++t2) {
        const int cur = t2 & 1;
        if (t2 < 31) {
            STG((t2 + 1) * 32, cur ^ 1);
            asm volatile("s_waitcnt vmcnt(3)" ::: "memory");
        } else {
            asm volatile("s_waitcnt vmcnt(0)" ::: "memory");
        }
        __syncthreads();
        bf16x8 af[2], bfv[4];
#pragma unroll
        for (int mi = 0; mi < 2; mi++)
            af[mi] = *(const bf16x8*)(&Asb[cur][(wr * 32 + mi * 16 + fr) * 32 + fg * 8]);
#pragma unroll
        for (int ni = 0; ni < 4; ni++)
            bfv[ni] = *(const bf16x8*)(&Bsb[cur][(wc * 64 + ni * 16 + fr) * 32 + fg * 8]);
#pragma unroll
        for (int mi = 0; mi < 2; mi++)
#pragma unroll
            for (int ni = 0; ni < 4; ni++)
                acc[mi][ni] = __builtin_amdgcn_mfma_f32_16x16x32_bf16(af[mi], bfv[ni], acc[mi][ni], 0, 0, 0);
        __syncthreads();
    }
#undef STG

#pragma unroll
    for (int ni = 0; ni < 4; ni++) {
        const int n = n0 + wc * 64 + ni * 16 + fr;
        const float bv = bias[n];
#pragma unroll
        for (int mi = 0; mi < 2; mi++) {
            const int mb = m0 + wr * 32 + mi * 16 + fg * 4;
            if constexpr (MODE == 1) {
                float* C = (float*)Cout;
#pragma unroll
                for (int r = 0; r < 4; r++) C[(size_t)(mb + r) * 1024 + n] = acc[mi][ni][r] + bv;
            } else if constexpr (MODE == 0) {
                unsigned short* C = (unsigned short*)Cout;
                const int h = n >> 6, hd = n & 63;
#pragma unroll
                for (int r = 0; r < 4; r++) {
                    const int m = mb + r;
                    const int bb = m >> 11, s = m & 2047;
                    C[(size_t)((bb * 16 + h) * 2048 + s) * 64 + hd] = f2bf(acc[mi][ni][r] + bv);
                }
            } else {  // MODE 2: vt[B,NH,HD,S] with per-64 k-slot permutation
                unsigned short* C = (unsigned short*)Cout;
                const int h = n >> 6, hd = n & 63;
                const int bb = mb >> 11, s = mb & 2047;
                const int blk = s >> 6, off = s & 63;
                const int pos = blk * 64 + (off >> 5) * 32 + ((off & 15) >> 2) * 8 + ((off >> 4) & 1) * 4;
                ushort4v pk;
                pk.x = f2bf(acc[mi][ni][0] + bv);
                pk.y = f2bf(acc[mi][ni][1] + bv);
                pk.z = f2bf(acc[mi][ni][2] + bv);
                pk.w = f2bf(acc[mi][ni][3] + bv);
                *(ushort4v*)(C + (size_t)((bb * 16 + h) * 64 + hd) * 2048 + pos) = pk;
            }
        }
    }
}

// ---------------- fused attention v8: ONE pass, 32q block, P in VGPRs, R4 store schedule ----------------
// Block = 32 q rows, 4 waves, wave w owns k in [w*512,(w+1)*512). QK^T computed ONCE;
// unnormalized exp kept as packed bf16 in 128 VGPRs/lane. Stores (normalized fp32, nt)
// interleaved per-kt with PV (permuted-V zero-shuffle). O normalized at the end.
__global__ __launch_bounds__(256, 2) void attn_kernel(const unsigned short* __restrict__ Qh,
                                                      const unsigned short* __restrict__ Kh,
                                                      const unsigned short* __restrict__ Vt,
                                                      unsigned short* __restrict__ Obuf,
                                                      float* __restrict__ AttnOut) {
    __shared__ float rpart[32][4];
    __shared__ float rinv_s[32];
    __shared__ float ored[32][68];

    const int i = blockIdx.x;
    const int qt = i & 63, bh = i >> 6;
    const int b = bh >> 4, h = bh & 15;
    const int q0 = qt * 32;
    const int t = threadIdx.x, w = t >> 6, l = t & 63;
    const int fr = l & 15, fg = l >> 4;
    const float SCL = 0.1803368801111f;          // 0.125 / ln(2)

    const unsigned short* qb = Qh + (size_t)(bh * 2048 + q0) * 64;
    bf16x8 qf[2][2];
#pragma unroll
    for (int qs = 0; qs < 2; qs++)
#pragma unroll
        for (int kc = 0; kc < 2; kc++)
            qf[qs][kc] = *(const bf16x8*)(qb + (size_t)(qs * 16 + fr) * 64 + kc * 32 + fg * 8);

    const unsigned short* kbase = Kh + ((size_t)bh * 2048 + w * 512) * 64;
    const unsigned short* vtb = Vt + (size_t)bh * 64 * 2048;

    // ---- single QK^T sweep: unnormalized exp packed bf16 in regs + row-sums ----
    unsigned p0[8][8], p1[8][8];
    float rs0 = 0.f, rs1 = 0.f;
#pragma unroll
    for (int kt = 0; kt < 8; ++kt) {
#pragma unroll
        for (int mt = 0; mt < 4; ++mt) {
            const unsigned short* kr = kbase + (size_t)(kt * 64 + mt * 16 + fr) * 64 + fg * 8;
            bf16x8 kf0 = *(const bf16x8*)kr;
            bf16x8 kf1 = *(const bf16x8*)(kr + 32);
            f32x4 d0 = {}, d1 = {};
            d0 = __builtin_amdgcn_mfma_f32_16x16x32_bf16(kf0, qf[0][0], d0, 0, 0, 0);
            d0 = __builtin_amdgcn_mfma_f32_16x16x32_bf16(kf1, qf[0][1], d0, 0, 0, 0);
            d1 = __builtin_amdgcn_mfma_f32_16x16x32_bf16(kf0, qf[1][0], d1, 0, 0, 0);
            d1 = __builtin_amdgcn_mfma_f32_16x16x32_bf16(kf1, qf[1][1], d1, 0, 0, 0);
            const float a0 = exp2f(d0[0] * SCL), a1 = exp2f(d0[1] * SCL);
            const float a2 = exp2f(d0[2] * SCL), a3 = exp2f(d0[3] * SCL);
            rs0 += (a0 + a1) + (a2 + a3);
            p0[kt][mt * 2] = cvtpk(a0, a1);
            p0[kt][mt * 2 + 1] = cvtpk(a2, a3);
            const float c0 = exp2f(d1[0] * SCL), c1 = exp2f(d1[1] * SCL);
            const float c2 = exp2f(d1[2] * SCL), c3 = exp2f(d1[3] * SCL);
            rs1 += (c0 + c1) + (c2 + c3);
            p1[kt][mt * 2] = cvtpk(c0, c1);
            p1[kt][mt * 2 + 1] = cvtpk(c2, c3);
        }
    }
    // ---- rinv ----
    rs0 += __shfl_xor(rs0, 16, 64); rs0 += __shfl_xor(rs0, 32, 64);
    rs1 += __shfl_xor(rs1, 16, 64); rs1 += __shfl_xor(rs1, 32, 64);
    if (l < 16) { rpart[l][w] = rs0; rpart[l + 16][w] = rs1; }
    __syncthreads();
    for (int j = t; j < 32 * 68; j += 256) (&ored[0][0])[j] = 0.f;
    if (t < 32) rinv_s[t] = 1.0f / (rpart[t][0] + rpart[t][1] + rpart[t][2] + rpart[t][3]);
    __syncthreads();
    const float ri0 = rinv_s[fr], ri1 = rinv_s[16 + fr];

    // ---- store + PV, interleaved per kt (R4's winning schedule) ----
    float* attnB0 = AttnOut + (size_t)bh * 2048 * 2048 + (size_t)(q0 + fr) * 2048 + w * 512;
    float* attnB1 = attnB0 + (size_t)16 * 2048;
    f32x4 opv[2][4] = {};
#pragma unroll
    for (int kt = 0; kt < 8; ++kt) {
#pragma unroll
        for (int mt = 0; mt < 4; ++mt) {
            const unsigned a = p0[kt][mt * 2], aa = p0[kt][mt * 2 + 1];
            f32x4 o;
            o[0] = __uint_as_float(a << 16) * ri0;
            o[1] = __uint_as_float(a & 0xffff0000u) * ri0;
            o[2] = __uint_as_float(aa << 16) * ri0;
            o[3] = __uint_as_float(aa & 0xffff0000u) * ri0;
            __builtin_nontemporal_store(o, (f32x4*)(attnB0 + kt * 64 + mt * 16 + fg * 4));
            const unsigned c = p1[kt][mt * 2], cc = p1[kt][mt * 2 + 1];
            f32x4 o1;
            o1[0] = __uint_as_float(c << 16) * ri1;
            o1[1] = __uint_as_float(c & 0xffff0000u) * ri1;
            o1[2] = __uint_as_float(cc << 16) * ri1;
            o1[3] = __uint_as_float(cc & 0xffff0000u) * ri1;
            __builtin_nontemporal_store(o1, (f32x4*)(attnB1 + kt * 64 + mt * 16 + fg * 4));
        }
#pragma unroll
        for (int kc = 0; kc < 2; ++kc) {
            union { unsigned u[4]; bf16x8 v; } pb0, pb1;
#pragma unroll
            for (int j = 0; j < 4; j++) { pb0.u[j] = p0[kt][4 * kc + j]; pb1.u[j] = p1[kt][4 * kc + j]; }
#pragma unroll
            for (int dt = 0; dt < 4; ++dt) {
                bf16x8 vf = *(const bf16x8*)(vtb + (size_t)(dt * 16 + fr) * 2048 + w * 512 + kt * 64 + kc * 32 + fg * 8);
                opv[0][dt] = __builtin_amdgcn_mfma_f32_16x16x32_bf16(vf, pb0.v, opv[0][dt], 0, 0, 0);
                opv[1][dt] = __builtin_amdgcn_mfma_f32_16x16x32_bf16(vf, pb1.v, opv[1][dt], 0, 0, 0);
            }
        }
    }

    // ---- cross-wave O reduction; O = ored * rinv ----
    __syncthreads();
    for (int ww = 0; ww < 4; ++ww) {
        if (w == ww) {
#pragma unroll
            for (int qs = 0; qs < 2; qs++)
#pragma unroll
                for (int dt = 0; dt < 4; dt++)
#pragma unroll
                    for (int r = 0; r < 4; r++)
                        ored[qs * 16 + fr][dt * 16 + 4 * fg + r] += opv[qs][dt][r];
        }
        __syncthreads();
    }
    {
        const int row = t >> 3, cb = (t & 7) * 8;
        const float rr = rinv_s[row];
        ushort8 pk;
#pragma unroll
        for (int j = 0; j < 8; j++) pk[j] = f2bf(ored[row][cb + j] * rr);
        *(ushort8*)(Obuf + (size_t)(b * 2048 + q0 + row) * 1024 + h * 64 + cb) = pk;
    }
}

extern "C" void kernel_launch(void* const* d_in, const int* in_sizes, int n_in,
                              void* d_out, int out_size, void* d_ws, size_t ws_size,
                              hipStream_t stream) {
    const float* q = (const float*)d_in[0];
    const float* k = (const float*)d_in[1];
    const float* v = (const float*)d_in[2];
    const float* wqw = (const float*)d_in[3];
    const float* wqb = (const float*)d_in[4];
    const float* wkw = (const float*)d_in[5];
    const float* wkb = (const float*)d_in[6];
    const float* wvw = (const float*)d_in[7];
    const float* wvb = (const float*)d_in[8];
    const float* wow = (const float*)d_in[9];
    const float* wob = (const float*)d_in[10];

    char* ws = (char*)d_ws;
    unsigned short* xbf  = (unsigned short*)(ws);              // 8 MB staging (reused q,k,v)
    unsigned short* wbf  = (unsigned short*)(ws + 8388608);    // 2 MB weight staging (reused)
    unsigned short* qh   = (unsigned short*)(ws + 10485760);   // [B,NH,S,HD] bf16
    unsigned short* kh   = (unsigned short*)(ws + 18874368);   // [B,NH,S,HD] bf16
    unsigned short* vt   = (unsigned short*)(ws + 27262976);   // [B,NH,HD,S] bf16, k-permuted
    unsigned short* obuf = (unsigned short*)(ws + 35651584);   // [B*S,H] bf16

    float* finalOut = (float*)d_out;
    float* attnOut = finalOut + 4194304;

    const int NX = 4194304, NW = 1048576;
    const int c2grid = (NX + NW) / 1024;
    dim3 gGrid(8, 64);

    cvt2_kernel<<<c2grid, 256, 0, stream>>>(q, xbf, NX, wqw, wbf, NW);
    gemm_bt<0><<<gGrid, 256, 0, stream>>>(xbf, wbf, wqb, qh);

    cvt2_kernel<<<c2grid, 256, 0, stream>>>(k, xbf, NX, wkw, wbf, NW);
    gemm_bt<0><<<gGrid, 256, 0, stream>>>(xbf, wbf, wkb, kh);

    cvt2_kernel<<<c2grid, 256, 0, stream>>>(v, xbf, NX, wvw, wbf, NW);
    gemm_bt<2><<<gGrid, 256, 0, stream>>>(xbf, wbf, wvb, vt);

    attn_kernel<<<2048, 256, 0, stream>>>(qh, kh, vt, obuf, attnOut);

    cvt_kernel<<<NW / 1024, 256, 0, stream>>>(wow, wbf, NW);
    gemm_bt<1><<<gGrid, 256, 0, stream>>>(obuf, wbf, wob, finalOut);
}